// Round 1
// baseline (249.865 us; speedup 1.0000x reference)
//
#include <hip/hip_runtime.h>
#include <cstdint>
#include <cstddef>

// One wave (64 lanes) per batch. Lane i owns row i (register copy) and
// column i (register copy) of x0 = exp(logits/T - max). Sinkhorn runs in
// diagonal-scaling form: x_t = diag(u) * x0 * diag(v); each half-iteration is
// a 64x64 matvec done with readlane-broadcast + v_fmac (no LDS anywhere).

__device__ __forceinline__ float rl(float x, int lane) {
    return __uint_as_float((unsigned)__builtin_amdgcn_readlane((int)__float_as_uint(x), lane));
}

#define GREEDY_CASE(R)                                                  \
  case (R): {                                                           \
    col[(R)] = -__builtin_inff();                                       \
    const int G_ = (R) >> 3;                                            \
    float nv_ = col[((R) >> 3) * 8]; int na_ = ((R) >> 3) * 8;          \
    _Pragma("unroll")                                                   \
    for (int k_ = 1; k_ < 8; ++k_) {                                    \
      float c_ = col[((R) >> 3) * 8 + k_];                              \
      if (c_ > nv_) { nv_ = c_; na_ = ((R) >> 3) * 8 + k_; }            \
    }                                                                   \
    gvv[G_] = nv_; gaa[G_] = na_;                                       \
  } break;

#define GC4(R) GREEDY_CASE(R) GREEDY_CASE((R)+1) GREEDY_CASE((R)+2) GREEDY_CASE((R)+3)

__global__ void __launch_bounds__(64)
sinkhorn_perm_kernel(const float* __restrict__ logits,
                     const float* __restrict__ ptemp,
                     float* __restrict__ out)
{
    const int b    = blockIdx.x;
    const int lane = threadIdx.x;
    const float* base = logits + (size_t)b * 4096;

    const float T    = ptemp[0] + 1e-6f;
    const float invT = 1.0f / T;          // IEEE divide (one-time)

    // ---- load row `lane`, scale by invT -------------------------------
    float row[64];
    {
        const float4* rp = (const float4*)(base + lane * 64);
        #pragma unroll
        for (int t = 0; t < 16; ++t) {
            float4 q = rp[t];
            row[4*t+0] = __fmul_rn(q.x, invT);
            row[4*t+1] = __fmul_rn(q.y, invT);
            row[4*t+2] = __fmul_rn(q.z, invT);
            row[4*t+3] = __fmul_rn(q.w, invT);
        }
    }

    // ---- global max over the 64x64 tile -------------------------------
    float mx = row[0];
    #pragma unroll
    for (int i = 1; i < 64; ++i) mx = fmaxf(mx, row[i]);
    #pragma unroll
    for (int w = 1; w <= 32; w <<= 1)
        mx = fmaxf(mx, __shfl_xor(mx, w, 64));

    // ---- x0 row copy: exp(scaled - mx) --------------------------------
    #pragma unroll
    for (int i = 0; i < 64; ++i)
        row[i] = __expf(__fsub_rn(row[i], mx));

    // ---- x0 column copy (coalesced across lanes at each i) ------------
    // Bitwise-identical op sequence to the row copy (no fp contraction).
    float col[64];
    #pragma unroll
    for (int i = 0; i < 64; ++i) {
        float raw = base[i * 64 + lane];
        col[i] = __expf(__fsub_rn(__fmul_rn(raw, invT), mx));
    }

    // ---- sinkhorn in diag(u) * X0 * diag(v) form ----------------------
    float u = 1.0f, v = 1.0f;
    for (int it = 0; it < 30; ++it) {
        // row phase: r_i = row_i . v  (v_j broadcast via readlane)
        float a0 = 0.f, a1 = 0.f, a2 = 0.f, a3 = 0.f;
        #pragma unroll
        for (int j = 0; j < 64; j += 4) {
            a0 = __builtin_fmaf(row[j+0], rl(v, j+0), a0);
            a1 = __builtin_fmaf(row[j+1], rl(v, j+1), a1);
            a2 = __builtin_fmaf(row[j+2], rl(v, j+2), a2);
            a3 = __builtin_fmaf(row[j+3], rl(v, j+3), a3);
        }
        float rs = __fadd_rn(__fadd_rn(a0, a1), __fadd_rn(a2, a3));
        u = u / __fadd_rn(__fmul_rn(u, rs), 1e-8f);   // IEEE divide

        // col phase: c_j = col_j . u  (updated u broadcast)
        a0 = a1 = a2 = a3 = 0.f;
        #pragma unroll
        for (int i = 0; i < 64; i += 4) {
            a0 = __builtin_fmaf(col[i+0], rl(u, i+0), a0);
            a1 = __builtin_fmaf(col[i+1], rl(u, i+1), a1);
            a2 = __builtin_fmaf(col[i+2], rl(u, i+2), a2);
            a3 = __builtin_fmaf(col[i+3], rl(u, i+3), a3);
        }
        float cs = __fadd_rn(__fadd_rn(a0, a1), __fadd_rn(a2, a3));
        v = v / __fadd_rn(__fmul_rn(v, cs), 1e-8f);
    }

    // ---- final scores: s[i][j] = u_i * x0[i][j] * v_j (lane j keeps col j)
    #pragma unroll
    for (int i = 0; i < 64; ++i)
        col[i] = __fmul_rn(__fmul_rn(col[i], rl(u, i)), v);

    // ---- greedy unique argmax (matches stable argsort(-s) order) ------
    // Per-lane (= per-column) max in 8 groups of 8 rows; strict '>' with
    // ascending scan keeps the smallest row on ties.
    float gvv[8]; int gaa[8];
    #pragma unroll
    for (int g = 0; g < 8; ++g) {
        float bv = col[8*g]; int ba = 8*g;
        #pragma unroll
        for (int k = 1; k < 8; ++k) {
            float c2 = col[8*g + k];
            if (c2 > bv) { bv = c2; ba = 8*g + k; }
        }
        gvv[g] = bv; gaa[g] = ba;
    }

    int  mycol  = 0;
    bool colDone = false;

    for (int step = 0; step < 64; ++step) {
        // column best over groups (ascending g + strict '>' => smallest row on tie)
        float bv = gvv[0]; int ba = gaa[0];
        #pragma unroll
        for (int g = 1; g < 8; ++g)
            if (gvv[g] > bv) { bv = gvv[g]; ba = gaa[g]; }
        if (colDone) bv = 0.0f;              // all active scores are > 0

        // pack (value desc, flat idx asc) into one u64 key
        unsigned flat = ((unsigned)ba << 6) | (unsigned)lane;   // r*64 + c
        unsigned long long key =
            ((unsigned long long)__float_as_uint(bv) << 12) | (4095u - flat);

        #pragma unroll
        for (int msk = 1; msk <= 32; msk <<= 1) {
            unsigned long long o = __shfl_xor(key, msk, 64);
            if (o > key) key = o;
        }

        unsigned wflat = 4095u - (unsigned)(key & 4095ull);
        int r = __builtin_amdgcn_readfirstlane((int)(wflat >> 6));  // uniform
        int c = (int)(wflat & 63u);

        if (lane == r) mycol  = c;      // lane r owns output row r
        if (lane == c) colDone = true;  // retire column c

        // poison row r in every lane's column copy + rescan its 8-group.
        // r is wave-uniform -> scalar jump table, all register accesses static.
        switch (r) {
            GC4(0)  GC4(4)  GC4(8)  GC4(12) GC4(16) GC4(20) GC4(24) GC4(28)
            GC4(32) GC4(36) GC4(40) GC4(44) GC4(48) GC4(52) GC4(56) GC4(60)
        }
    }

    // ---- write hard permutation row (lane i -> row i) -----------------
    float* orow = out + (size_t)b * 4096 + lane * 64;
    #pragma unroll
    for (int t = 0; t < 16; ++t) {
        float4 q;
        q.x = (4*t+0 == mycol) ? 1.0f : 0.0f;
        q.y = (4*t+1 == mycol) ? 1.0f : 0.0f;
        q.z = (4*t+2 == mycol) ? 1.0f : 0.0f;
        q.w = (4*t+3 == mycol) ? 1.0f : 0.0f;
        ((float4*)orow)[t] = q;
    }
}

extern "C" void kernel_launch(void* const* d_in, const int* in_sizes, int n_in,
                              void* d_out, int out_size, void* d_ws, size_t ws_size,
                              hipStream_t stream) {
    const float* logits = (const float*)d_in[0];
    const float* ptemp  = (const float*)d_in[1];
    float* out = (float*)d_out;
    const int B = in_sizes[0] / 4096;   // 4096 = 64*64 elements per batch
    sinkhorn_perm_kernel<<<B, 64, 0, stream>>>(logits, ptemp, out);
}

// Round 2
// 240.082 us; speedup vs baseline: 1.0407x; 1.0407x over previous
//
#include <hip/hip_runtime.h>
#include <cstdint>
#include <cstddef>

// One wave (64 lanes) per batch (B=4096, N=K=64).
// Sinkhorn in diagonal form: x_t = diag(u) * X0 * diag(v); each half-iteration
// is a 64x64 matvec: lane i holds row i (regs), lane j holds col j (regs);
// the 64-wide broadcast of u/v goes through LDS as float4 reads (DS pipe)
// instead of 64 v_readlane (VALU pipe). Greedy unique-argmax keeps row
// liveness in a wave-uniform u64 bitmask (SGPRs) + per-lane 8-group maxima;
// retiring a row rescans only one 8-element group (8-case uniform switch).

#define TROW 68  // LDS transpose row stride in floats: 272 B = 16B-aligned,
                 // 68 % 32 banks -> lanes land on distinct bank groups

#define RESCAN(G)                                                            \
  {                                                                          \
    float nv_ = -__builtin_inff(); int na_ = (G) * 8;                        \
    _Pragma("unroll")                                                        \
    for (int k_ = 0; k_ < 8; ++k_) {                                         \
      const int idx_ = (G) * 8 + k_;                                         \
      float vk_ = ((rowmask >> idx_) & 1ull) ? col[idx_]                     \
                                             : -__builtin_inff();            \
      if (vk_ > nv_) { nv_ = vk_; na_ = idx_; }                              \
    }                                                                        \
    gv[(G)] = nv_; ga[(G)] = na_;                                            \
  }

__global__ void __launch_bounds__(64, 3)
sinkhorn_perm_kernel(const float* __restrict__ logits,
                     const float* __restrict__ ptemp,
                     float* __restrict__ out)
{
    const int b    = blockIdx.x;
    const int lane = threadIdx.x;
    const float* base = logits + (size_t)b * 4096;

    __shared__ float lds[16 * TROW];   // 4352 B; low 64 floats reused for broadcasts

    const float T    = ptemp[0] + 1e-6f;
    const float invT = 1.0f / T;       // IEEE divide (one-time)

    // ---- load row `lane`, scale by invT -------------------------------
    float row[64];
    {
        const float4* rp = (const float4*)(base + lane * 64);
        #pragma unroll
        for (int t = 0; t < 16; ++t) {
            float4 q = rp[t];
            row[4*t+0] = __fmul_rn(q.x, invT);
            row[4*t+1] = __fmul_rn(q.y, invT);
            row[4*t+2] = __fmul_rn(q.z, invT);
            row[4*t+3] = __fmul_rn(q.w, invT);
        }
    }

    // ---- global max over the 64x64 tile -------------------------------
    float mx = row[0];
    #pragma unroll
    for (int i = 1; i < 64; ++i) mx = fmaxf(mx, row[i]);
    #pragma unroll
    for (int w = 1; w <= 32; w <<= 1)
        mx = fmaxf(mx, __shfl_xor(mx, w, 64));

    // ---- x0 row copy: exp(scaled - mx) --------------------------------
    #pragma unroll
    for (int i = 0; i < 64; ++i)
        row[i] = __expf(__fsub_rn(row[i], mx));

    // ---- column copy via LDS transpose (bitwise-identical values) -----
    float col[64];
    #pragma unroll
    for (int ch = 0; ch < 4; ++ch) {
        if ((lane >> 4) == ch) {
            float4* wp = (float4*)&lds[(lane & 15) * TROW];
            #pragma unroll
            for (int t = 0; t < 16; ++t)
                wp[t] = make_float4(row[4*t], row[4*t+1], row[4*t+2], row[4*t+3]);
        }
        __syncthreads();
        #pragma unroll
        for (int t = 0; t < 16; ++t)
            col[ch*16 + t] = lds[t * TROW + lane];
        __syncthreads();
    }

    // ---- sinkhorn in diag(u) * X0 * diag(v) form ----------------------
    float u = 1.0f, v = 1.0f;
    for (int it = 0; it < 30; ++it) {
        // row phase: rs_i = row_i . v   (v broadcast via LDS float4 reads)
        lds[lane] = v;
        __syncthreads();
        float a0 = 0.f, a1 = 0.f, a2 = 0.f, a3 = 0.f;
        #pragma unroll
        for (int t = 0; t < 16; ++t) {
            float4 q = ((const float4*)lds)[t];
            a0 = __builtin_fmaf(row[4*t+0], q.x, a0);
            a1 = __builtin_fmaf(row[4*t+1], q.y, a1);
            a2 = __builtin_fmaf(row[4*t+2], q.z, a2);
            a3 = __builtin_fmaf(row[4*t+3], q.w, a3);
        }
        float rs = __fadd_rn(__fadd_rn(a0, a1), __fadd_rn(a2, a3));
        u = u / __fadd_rn(__fmul_rn(u, rs), 1e-8f);   // IEEE divide
        __syncthreads();

        // col phase: cs_j = col_j . u  (updated u broadcast)
        lds[lane] = u;
        __syncthreads();
        a0 = a1 = a2 = a3 = 0.f;
        #pragma unroll
        for (int t = 0; t < 16; ++t) {
            float4 q = ((const float4*)lds)[t];
            a0 = __builtin_fmaf(col[4*t+0], q.x, a0);
            a1 = __builtin_fmaf(col[4*t+1], q.y, a1);
            a2 = __builtin_fmaf(col[4*t+2], q.z, a2);
            a3 = __builtin_fmaf(col[4*t+3], q.w, a3);
        }
        float cs = __fadd_rn(__fadd_rn(a0, a1), __fadd_rn(a2, a3));
        v = v / __fadd_rn(__fmul_rn(v, cs), 1e-8f);
        __syncthreads();
    }

    // ---- final scores: s[i][j] = (x0[i][j] * u_i) * v_j ----------------
    lds[lane] = u;
    __syncthreads();
    #pragma unroll
    for (int t = 0; t < 16; ++t) {
        float4 q = ((const float4*)lds)[t];
        col[4*t+0] = __fmul_rn(__fmul_rn(col[4*t+0], q.x), v);
        col[4*t+1] = __fmul_rn(__fmul_rn(col[4*t+1], q.y), v);
        col[4*t+2] = __fmul_rn(__fmul_rn(col[4*t+2], q.z), v);
        col[4*t+3] = __fmul_rn(__fmul_rn(col[4*t+3], q.w), v);
    }

    // ---- greedy unique argmax (matches stable argsort(-s) order) ------
    float gv[8]; int ga[8];
    #pragma unroll
    for (int g = 0; g < 8; ++g) {
        float bv2 = col[8*g]; int ba2 = 8*g;
        #pragma unroll
        for (int k = 1; k < 8; ++k)
            if (col[8*g+k] > bv2) { bv2 = col[8*g+k]; ba2 = 8*g+k; }
        gv[g] = bv2; ga[g] = ba2;
    }

    unsigned long long rowmask = ~0ull;   // wave-uniform -> SGPR pair
    int  mycol = 0;
    bool done  = false;

    for (int step = 0; step < 64; ++step) {
        // per-lane best over 8 groups (ascending + strict '>' => min row on tie)
        float bv = gv[0]; int ba = ga[0];
        #pragma unroll
        for (int g2 = 1; g2 < 8; ++g2)
            if (gv[g2] > bv) { bv = gv[g2]; ba = ga[g2]; }

        // pack (value desc, flat idx asc) into one u64 key
        unsigned flat = ((unsigned)ba << 6) | (unsigned)lane;   // r*64 + c
        unsigned long long key =
            ((unsigned long long)__float_as_uint(bv) << 12) | (4095u - flat);
        if (done) key = 0ull;

        #pragma unroll
        for (int m = 1; m <= 32; m <<= 1) {
            unsigned long long o = __shfl_xor(key, m, 64);
            if (o > key) key = o;
        }

        unsigned wflat = 4095u - (unsigned)(key & 4095ull);
        int r = __builtin_amdgcn_readfirstlane((int)(wflat >> 6));  // uniform
        int c = (int)(wflat & 63u);

        if (lane == r) mycol = c;      // lane r owns output row r
        if (lane == c) done  = true;   // retire column c
        rowmask &= ~(1ull << r);       // retire row r (scalar ops)

        // rescan only the 8-row group containing r (r>>3 is wave-uniform)
        switch (r >> 3) {
            case 0: RESCAN(0) break;
            case 1: RESCAN(1) break;
            case 2: RESCAN(2) break;
            case 3: RESCAN(3) break;
            case 4: RESCAN(4) break;
            case 5: RESCAN(5) break;
            case 6: RESCAN(6) break;
            case 7: RESCAN(7) break;
        }
    }

    // ---- write hard permutation row (lane i -> row i) -----------------
    float* orow = out + (size_t)b * 4096 + lane * 64;
    #pragma unroll
    for (int t = 0; t < 16; ++t) {
        float4 q;
        q.x = (4*t+0 == mycol) ? 1.0f : 0.0f;
        q.y = (4*t+1 == mycol) ? 1.0f : 0.0f;
        q.z = (4*t+2 == mycol) ? 1.0f : 0.0f;
        q.w = (4*t+3 == mycol) ? 1.0f : 0.0f;
        ((float4*)orow)[t] = q;
    }
}

extern "C" void kernel_launch(void* const* d_in, const int* in_sizes, int n_in,
                              void* d_out, int out_size, void* d_ws, size_t ws_size,
                              hipStream_t stream) {
    const float* logits = (const float*)d_in[0];
    const float* ptemp  = (const float*)d_in[1];
    float* out = (float*)d_out;
    const int B = in_sizes[0] / 4096;   // 64*64 elements per batch
    sinkhorn_perm_kernel<<<B, 64, 0, stream>>>(logits, ptemp, out);
}